// Round 4
// baseline (165.450 us; speedup 1.0000x reference)
//
#include <hip/hip_runtime.h>
#include <hip/hip_bf16.h>
#include <cmath>

// NPHierarchicalTransitionPrior — round 4: barrier-free wave-private pipeline.
// Every GEMM is N-split: a wave owns 16 sample-columns; full weight matrices
// live in registers as A-fragments. The D-layout -> B-layout repack between
// chained GEMMs is a wave-private LDS roundtrip (in-order DS pipe, no
// __syncthreads). b1 folded into K-pad (V[IN]=1, W1[:,IN]=b1).
//   GEMM1: H1pre = W1(64xIN+1 pad32) x V(32x16)      4 MFMA
//   GEMM2: H2pre = W2(64x64) x H1(64x16)             8 MFMA
//   GEMM3: U1    = W2^T x U2                         8 MFMA
//   GEMM4: G     = W1^T x (D1.U1)                    2|4 MFMA
// Per-wave LDS frag scratch: addr(k, r) = (k>>3)*256 + r*16 + (k&7)*2.

namespace {

using bf16x8 = __attribute__((ext_vector_type(8))) short;
using f32x4  = __attribute__((ext_vector_type(4))) float;
using f32x2  = __attribute__((ext_vector_type(2))) float;
using bf2    = __attribute__((ext_vector_type(2))) __bf16;
using u32x2  = __attribute__((ext_vector_type(2))) unsigned;
using u32x4  = __attribute__((ext_vector_type(4))) unsigned;

constexpr int NB = 256, NT = 512, TROW = 513, DIN = 16, HID = 64;
constexpr int NSAMP = NB * NT;                                // 131072
constexpr size_t OFF_SUMLOG = (size_t)NSAMP * DIN;            // 2097152
constexpr size_t OFF_H0     = OFF_SUMLOG + NB;                // 2097408
constexpr size_t OFF_H1     = OFF_H0 + (size_t)8 * NSAMP * 8; // 10486016

struct SMem {
    alignas(16) char scr[4][6144];   // per wave: H1 @0, U2 @2048, U1m @4096
    float slogW[4];
};

__device__ __forceinline__ short b16(float f) {
    return __builtin_bit_cast(short, (__bf16)f);
}
__device__ __forceinline__ unsigned pk2(float a, float b) {   // v_cvt_pk_bf16_f32
    f32x2 t{a, b};
    return __builtin_bit_cast(unsigned, __builtin_convertvector(t, bf2));
}
__device__ __forceinline__ bf16x8 mkfrag(unsigned a, unsigned b, unsigned c, unsigned d) {
    u32x4 t{a, b, c, d};
    return __builtin_bit_cast(bf16x8, t);
}
__device__ __forceinline__ f32x4 mfma16(bf16x8 a, bf16x8 b, f32x4 c) {
    return __builtin_amdgcn_mfma_f32_16x16x32_bf16(a, b, c, 0, 0, 0);
}
// write D tile m (rows 16m+4q+e, col r) as bf16 quad -> frag scratch
__device__ __forceinline__ void wrD(char* buf, int m, int q, int r, f32x4 v) {
    u32x2 t{pk2(v[0], v[1]), pk2(v[2], v[3])};
    *reinterpret_cast<u32x2*>(buf + ((2 * m + (q >> 1)) << 8) + (r << 4) + ((q & 1) << 3)) = t;
}
// read B-frag (k=32ks+8q+e, col r) from frag scratch
__device__ __forceinline__ bf16x8 rdB(const char* buf, int ks, int q, int r) {
    return *reinterpret_cast<const bf16x8*>(buf + (((ks << 2) + q) << 8) + (r << 4));
}

template<int L, int IN>
__device__ __forceinline__ void mlp_impl(
    SMem& sm, int d, int b,
    const float* __restrict__ x,
    const float* __restrict__ gW1, const float* __restrict__ gb1,
    const float* __restrict__ gW2, const float* __restrict__ gb2,
    const float* __restrict__ gW3, const float* __restrict__ gb3,
    float* __restrict__ out)
{
    const int tid = threadIdx.x;
    const int w = tid >> 6, lane = tid & 63;
    const int q = lane >> 4, r = lane & 15;
    char* scr = sm.scr[w];

    // ---- full weight set as A-fragments (A[row=16m+r][k=8q+e])
    bf16x8 aW1[4];                      // W1 with b1 folded at k==IN
    #pragma unroll
    for (int m = 0; m < 4; ++m) {
        const float* p  = gW1 + (size_t)(d * HID + 16 * m + r) * IN;
        const float  bb = gb1[d * HID + 16 * m + r];
        #pragma unroll
        for (int e = 0; e < 8; ++e) {
            int k = 8 * q + e;
            float v = (k < IN) ? p[k] : ((k == IN) ? bb : 0.0f);
            aW1[m][e] = b16(v);
        }
    }
    bf16x8 aW2[4][2], aW2T[4][2];
    #pragma unroll
    for (int m = 0; m < 4; ++m) {
        #pragma unroll
        for (int ks = 0; ks < 2; ++ks) {
            const float* p = gW2 + (size_t)d * HID * HID
                           + (size_t)(16 * m + r) * HID + 32 * ks + 8 * q;
            f32x4 u0 = *reinterpret_cast<const f32x4*>(p);
            f32x4 u1 = *reinterpret_cast<const f32x4*>(p + 4);
            aW2[m][ks] = mkfrag(pk2(u0[0], u0[1]), pk2(u0[2], u0[3]),
                                pk2(u1[0], u1[1]), pk2(u1[2], u1[3]));
            const float* pt = gW2 + (size_t)d * HID * HID
                            + (size_t)(32 * ks + 8 * q) * HID + 16 * m + r;
            #pragma unroll
            for (int e = 0; e < 8; ++e) aW2T[m][ks][e] = b16(pt[(size_t)e * HID]);
        }
    }
    constexpr int NMT = (IN > 16) ? 2 : 1;
    bf16x8 aW1T[NMT][2];                // W1^T rows = grad dims (zero past IN)
    #pragma unroll
    for (int mt = 0; mt < NMT; ++mt) {
        const int i = 16 * mt + r;
        #pragma unroll
        for (int ks = 0; ks < 2; ++ks) {
            const float* pt = gW1 + (size_t)d * HID * IN
                            + (size_t)(32 * ks + 8 * q) * IN + i;
            #pragma unroll
            for (int e = 0; e < 8; ++e)
                aW1T[mt][ks][e] = (i < IN) ? b16(pt[(size_t)e * IN]) : (short)0;
        }
    }
    f32x4 c2i[4], w3r[4], w3s[4];
    #pragma unroll
    for (int m = 0; m < 4; ++m) {
        c2i[m] = *reinterpret_cast<const f32x4*>(gb2 + d * HID + 16 * m + 4 * q);
        w3r[m] = *reinterpret_cast<const f32x4*>(gW3 + d * HID + 16 * m + 4 * q);
        #pragma unroll
        for (int e = 0; e < 4; ++e) w3s[m][e] = 0.01f * w3r[m][e];
    }
    const float b3v = gb3[d];

    const float* xb = x + (size_t)b * TROW * DIN;
    float lg = 0.0f;
    const f32x4 zero = {0.0f, 0.0f, 0.0f, 0.0f};

    for (int ps = 0; ps < 8; ++ps) {
        const int t = ps * 64 + 16 * w + r;       // this lane's sample column
        const float* yyp = xb + (size_t)t * DIN;  // xx = yyp + 16

        // ---- build V B-frag (k=8q+e, col r); b1-pad row k==IN gets 1.0
        float f0=0, f1=0, f2=0, f3=0, f4=0, f5=0, f6=0, f7=0;
        if constexpr (L == 0) {
            if (q == 0) {                          // k0..7 = yy[8..15]
                f32x4 u0 = *reinterpret_cast<const f32x4*>(yyp + 8);
                f32x4 u1 = *reinterpret_cast<const f32x4*>(yyp + 12);
                f0=u0[0]; f1=u0[1]; f2=u0[2]; f3=u0[3];
                f4=u1[0]; f5=u1[1]; f6=u1[2]; f7=u1[3];
            } else if (q == 1) {                   // k8 = xx[8+d], k9 = 1 (b1)
                f0 = yyp[DIN + 8 + d];
                f1 = 1.0f;
            }
        } else {
            if (q == 0) {                          // k0..7 = yy[0..7]
                f32x4 u0 = *reinterpret_cast<const f32x4*>(yyp);
                f32x4 u1 = *reinterpret_cast<const f32x4*>(yyp + 4);
                f0=u0[0]; f1=u0[1]; f2=u0[2]; f3=u0[3];
                f4=u1[0]; f5=u1[1]; f6=u1[2]; f7=u1[3];
            } else if (q == 1) {                   // k8..15 = xx[8..15]
                f32x4 u0 = *reinterpret_cast<const f32x4*>(yyp + 24);
                f32x4 u1 = *reinterpret_cast<const f32x4*>(yyp + 28);
                f0=u0[0]; f1=u0[1]; f2=u0[2]; f3=u0[3];
                f4=u1[0]; f5=u1[1]; f6=u1[2]; f7=u1[3];
            } else if (q == 2) {                   // k16 = xx[d], k17 = 1 (b1)
                f0 = yyp[DIN + d];
                f1 = 1.0f;
            }
        }
        bf16x8 bv = mkfrag(pk2(f0,f1), pk2(f2,f3), pk2(f4,f5), pk2(f6,f7));

        // ---- GEMM1 -> H1 (private scratch), keep d1 in-register
        f32x4 d1v[4];
        #pragma unroll
        for (int m = 0; m < 4; ++m) {
            f32x4 acc = mfma16(aW1[m], bv, zero);
            f32x4 h;
            #pragma unroll
            for (int e = 0; e < 4; ++e) {
                float dd = (acc[e] >= 0.0f) ? 1.0f : 0.01f;
                d1v[m][e] = dd;
                h[e] = acc[e] * dd;
            }
            wrD(scr, m, q, r, h);
        }
        bf16x8 bh0 = rdB(scr, 0, q, r), bh1 = rdB(scr, 1, q, r);

        // ---- GEMM2 -> residual partial + U2
        float pr = 0.0f;
        #pragma unroll
        for (int m = 0; m < 4; ++m) {
            f32x4 acc = mfma16(aW2[m][0], bh0, c2i[m]);
            acc = mfma16(aW2[m][1], bh1, acc);
            f32x4 u2;
            #pragma unroll
            for (int e = 0; e < 4; ++e) {
                u2[e] = (acc[e] >= 0.0f) ? w3r[m][e] : w3s[m][e];  // w3 * leaky'
                pr = fmaf(u2[e], acc[e], pr);                      // == w3 * h2
            }
            wrD(scr + 2048, m, q, r, u2);
        }
        pr += __shfl_xor(pr, 16, 64);
        pr += __shfl_xor(pr, 32, 64);
        if (q == 0) out[((size_t)b * NT + t) * DIN + (L * 8 + d)] = pr + b3v;
        bf16x8 bu0 = rdB(scr + 2048, 0, q, r), bu1 = rdB(scr + 2048, 1, q, r);

        // ---- GEMM3 -> U1m (mask by in-register d1)
        #pragma unroll
        for (int m = 0; m < 4; ++m) {
            f32x4 acc = mfma16(aW2T[m][0], bu0, zero);
            acc = mfma16(aW2T[m][1], bu1, acc);
            f32x4 u;
            #pragma unroll
            for (int e = 0; e < 4; ++e) u[e] = acc[e] * d1v[m][e];
            wrD(scr + 4096, m, q, r, u);
        }
        bf16x8 bg0 = rdB(scr + 4096, 0, q, r), bg1 = rdB(scr + 4096, 1, q, r);

        // ---- GEMM4 -> grads + logdet term
        f32x4 g0 = mfma16(aW1T[0][0], bg0, zero);
        g0 = mfma16(aW1T[0][1], bg1, g0);
        const size_t nglob = (size_t)b * NT + t;
        if constexpr (L == 1) {
            f32x4 g1 = mfma16(aW1T[1][0], bg0, zero);
            g1 = mfma16(aW1T[1][1], bg1, g1);
            *reinterpret_cast<f32x4*>(out + OFF_H1 + ((size_t)d * NSAMP + nglob) * 16 + 4 * q) = g0;
            if (q == 0) lg += logf(fabsf(g1[0]));          // grad row 16 = xcol
        } else {
            if (q < 2)
                *reinterpret_cast<f32x4*>(out + OFF_H0 + ((size_t)d * NSAMP + nglob) * 8 + 4 * q) = g0;
            if (q == 2) lg += logf(fabsf(g0[0]));          // grad row 8 = xcol
        }
    }

    // ---- epilogue: logdet reduce (only sync in the kernel)
    #pragma unroll
    for (int off = 1; off < 64; off <<= 1) lg += __shfl_xor(lg, off, 64);
    if (lane == 0) sm.slogW[w] = lg;
    __syncthreads();
    if (tid == 0)
        atomicAdd(out + OFF_SUMLOG + b,
                  sm.slogW[0] + sm.slogW[1] + sm.slogW[2] + sm.slogW[3]);
}

__global__ void zero_sumlog_kernel(float* __restrict__ out) {
    out[OFF_SUMLOG + threadIdx.x] = 0.0f;
}

__global__ __launch_bounds__(256, 2) void mlp_mfma_kernel(
    const float* __restrict__ x,
    const float* __restrict__ l0W1, const float* __restrict__ l0b1,
    const float* __restrict__ l0W2, const float* __restrict__ l0b2,
    const float* __restrict__ l0W3, const float* __restrict__ l0b3,
    const float* __restrict__ l1W1, const float* __restrict__ l1b1,
    const float* __restrict__ l1W2, const float* __restrict__ l1b2,
    const float* __restrict__ l1W3, const float* __restrict__ l1b3,
    float* __restrict__ out)
{
    __shared__ SMem sm;
    // XCD-aware decode: XCD k owns batch rows [32k, 32k+32) for all 16 (L,d)
    // units -> x slice + residual lines + weights live in one L2.
    const int xcd = blockIdx.x & 7;
    const int idx = blockIdx.x >> 3;         // 0..511
    const int b   = xcd * 32 + (idx & 31);
    const int uld = idx >> 5;                // 0..15
    if (uld < 8)
        mlp_impl<0, 9>(sm, uld, b, x, l0W1, l0b1, l0W2, l0b2, l0W3, l0b3, out);
    else
        mlp_impl<1, 17>(sm, uld - 8, b, x, l1W1, l1b1, l1W2, l1b2, l1W3, l1b3, out);
}

} // namespace

extern "C" void kernel_launch(void* const* d_in, const int* in_sizes, int n_in,
                              void* d_out, int out_size, void* d_ws, size_t ws_size,
                              hipStream_t stream) {
    const float* x = (const float*)d_in[0];
    // d_in[1] = alphas — unused by the reference outputs
    float* out = (float*)d_out;

    zero_sumlog_kernel<<<1, 256, 0, stream>>>(out);
    mlp_mfma_kernel<<<4096, 256, 0, stream>>>(
        x,
        (const float*)d_in[2],  (const float*)d_in[3],  (const float*)d_in[4],
        (const float*)d_in[5],  (const float*)d_in[6],  (const float*)d_in[7],
        (const float*)d_in[8],  (const float*)d_in[9],  (const float*)d_in[10],
        (const float*)d_in[11], (const float*)d_in[12], (const float*)d_in[13],
        out);
}